// Round 7
// baseline (489.636 us; speedup 1.0000x reference)
//
#include <hip/hip_runtime.h>
#include <cfloat>

#define NUM_EMB 50
#define EMB_DIM 192
#define ESTRIDE 196  // padded LDS stride (rows 16B-aligned; row base rotates banks)

// ((r0+r1)+(r2+r3))+((r4+r5)+(r6+r7)) — numpy's 8-accumulator combine tree
__device__ __forceinline__ float np_tree8(const float r[8]) {
#pragma clang fp contract(off)
    return ((r[0] + r[1]) + (r[2] + r[3])) + ((r[4] + r[5]) + (r[6] + r[7]));
}

// Bit-exact replica of np.sum(v*v) over 192 contiguous floats:
// pairwise halves of 96, each = 8 stride-8 accumulators + combine tree;
// products rounded separately (contract off).
__device__ float np_sumsq_192(const float* __restrict__ p) {
#pragma clang fp contract(off)
    float tot[2];
#pragma unroll
    for (int h = 0; h < 2; ++h) {
        float r[8];
#pragma unroll
        for (int l = 0; l < 8; ++l) r[l] = 0.f;
        const float* q = p + h * 96;
        for (int t = 0; t < 12; ++t)
#pragma unroll
            for (int l = 0; l < 8; ++l) {
                float v = q[t * 8 + l];
                float pr = v * v;
                r[l] = r[l] + pr;
            }
        tot[h] = np_tree8(r);
    }
    return tot[0] + tot[1];
}

// Pin a float4 pair in VGPRs with one asm node (8 operands) — blocks remat of
// the originating loads while keeping the asm-node count low for the allocator.
#define PIN2(u, v) asm volatile("" : "+v"(u.x), "+v"(u.y), "+v"(u.z), "+v"(u.w), \
                                      "+v"(v.x), "+v"(v.y), "+v"(v.z), "+v"(v.w))

// Process embeddings [K0, K0+KN) for 4 rows. acc is local (static-indexed via
// full ki-unroll); best/bidx updated in ascending-k order with strict < so the
// incremental argmin is bit-identical to a full 50-way first-index argmin.
// SUMSQ pass also computes a_r = np.sum(x_r*x_r) (numpy pairwise structure).
template<int K0, int KN, bool SUMSQ>
__device__ __forceinline__ void process_kblock(
    const float4* __restrict__ xg0, const float4* __restrict__ xg1,
    const float4* __restrict__ xg2, const float4* __restrict__ xg3,
    const float* __restrict__ sE, const float* __restrict__ sB,
    float& a0, float& a1, float& a2, float& a3,
    float& best0, float& best1, float& best2, float& best3,
    int& bidx0, int& bidx1, int& bidx2, int& bidx3)
{
    float acc0[KN], acc1[KN], acc2[KN], acc3[KN];
#pragma unroll
    for (int ki = 0; ki < KN; ++ki) { acc0[ki] = 0.f; acc1[ki] = 0.f; acc2[ki] = 0.f; acc3[ki] = 0.f; }

    float rA0[8], rA1[8], rA2[8], rA3[8];
    float aH00, aH01, aH10, aH11, aH20, aH21, aH30, aH31;

#pragma unroll 1
    for (int m = 0; m < 6; ++m) {  // 6 chunks of 32 floats per row
        float4 fa[8], fb[8], fc[8], fd[8];
#pragma unroll
        for (int q = 0; q < 8; ++q) fa[q] = xg0[m * 8 + q];
#pragma unroll
        for (int q = 0; q < 8; ++q) fb[q] = xg1[m * 8 + q];
#pragma unroll
        for (int q = 0; q < 8; ++q) fc[q] = xg2[m * 8 + q];
#pragma unroll
        for (int q = 0; q < 8; ++q) fd[q] = xg3[m * 8 + q];
        // Pin all chunks: rematerializing these loads inside the k-body is illegal.
#pragma unroll
        for (int q = 0; q < 8; q += 2) {
            PIN2(fa[q], fa[q + 1]);
            PIN2(fb[q], fb[q + 1]);
            PIN2(fc[q], fc[q + 1]);
            PIN2(fd[q], fd[q + 1]);
        }

        if constexpr (SUMSQ) {
            // ||x||^2 partials, numpy pairwise structure (halves at m=0..2, 3..5)
            if ((m % 3) == 0) {
#pragma unroll
                for (int l = 0; l < 8; ++l) { rA0[l] = 0.f; rA1[l] = 0.f; rA2[l] = 0.f; rA3[l] = 0.f; }
            }
            {
#pragma clang fp contract(off)
#pragma unroll
                for (int q = 0; q < 8; ++q) {
                    float p0 = fa[q].x * fa[q].x; rA0[(q * 4 + 0) & 7] = rA0[(q * 4 + 0) & 7] + p0;
                    float p1 = fa[q].y * fa[q].y; rA0[(q * 4 + 1) & 7] = rA0[(q * 4 + 1) & 7] + p1;
                    float p2 = fa[q].z * fa[q].z; rA0[(q * 4 + 2) & 7] = rA0[(q * 4 + 2) & 7] + p2;
                    float p3 = fa[q].w * fa[q].w; rA0[(q * 4 + 3) & 7] = rA0[(q * 4 + 3) & 7] + p3;
                }
#pragma unroll
                for (int q = 0; q < 8; ++q) {
                    float p0 = fb[q].x * fb[q].x; rA1[(q * 4 + 0) & 7] = rA1[(q * 4 + 0) & 7] + p0;
                    float p1 = fb[q].y * fb[q].y; rA1[(q * 4 + 1) & 7] = rA1[(q * 4 + 1) & 7] + p1;
                    float p2 = fb[q].z * fb[q].z; rA1[(q * 4 + 2) & 7] = rA1[(q * 4 + 2) & 7] + p2;
                    float p3 = fb[q].w * fb[q].w; rA1[(q * 4 + 3) & 7] = rA1[(q * 4 + 3) & 7] + p3;
                }
#pragma unroll
                for (int q = 0; q < 8; ++q) {
                    float p0 = fc[q].x * fc[q].x; rA2[(q * 4 + 0) & 7] = rA2[(q * 4 + 0) & 7] + p0;
                    float p1 = fc[q].y * fc[q].y; rA2[(q * 4 + 1) & 7] = rA2[(q * 4 + 1) & 7] + p1;
                    float p2 = fc[q].z * fc[q].z; rA2[(q * 4 + 2) & 7] = rA2[(q * 4 + 2) & 7] + p2;
                    float p3 = fc[q].w * fc[q].w; rA2[(q * 4 + 3) & 7] = rA2[(q * 4 + 3) & 7] + p3;
                }
#pragma unroll
                for (int q = 0; q < 8; ++q) {
                    float p0 = fd[q].x * fd[q].x; rA3[(q * 4 + 0) & 7] = rA3[(q * 4 + 0) & 7] + p0;
                    float p1 = fd[q].y * fd[q].y; rA3[(q * 4 + 1) & 7] = rA3[(q * 4 + 1) & 7] + p1;
                    float p2 = fd[q].z * fd[q].z; rA3[(q * 4 + 2) & 7] = rA3[(q * 4 + 2) & 7] + p2;
                    float p3 = fd[q].w * fd[q].w; rA3[(q * 4 + 3) & 7] = rA3[(q * 4 + 3) & 7] + p3;
                }
            }
            if (m == 2) { aH00 = np_tree8(rA0); aH10 = np_tree8(rA1); aH20 = np_tree8(rA2); aH30 = np_tree8(rA3); }
            if (m == 5) { aH01 = np_tree8(rA0); aH11 = np_tree8(rA1); aH21 = np_tree8(rA2); aH31 = np_tree8(rA3); }
        }

        // Per ki: 8 broadcast ds_read_b128, reused by all FOUR rows' chains
        // (j ascending per k — bit-exact numpy/BLAS order). 4 independent
        // chains x 32 FMAs = ILP 4, covers DS latency at 1 wave/SIMD.
        const float* ebase = &sE[K0 * ESTRIDE + m * 32];
#pragma unroll
        for (int ki = 0; ki < KN; ++ki) {
            const float* ek = ebase + ki * ESTRIDE;
            float4 e4[8];
#pragma unroll
            for (int h = 0; h < 8; ++h) e4[h] = *(const float4*)&ek[h * 4];
#pragma unroll
            for (int h = 0; h < 8; ++h) {
                acc0[ki] = __builtin_fmaf(fa[h].x, e4[h].x, acc0[ki]);
                acc0[ki] = __builtin_fmaf(fa[h].y, e4[h].y, acc0[ki]);
                acc0[ki] = __builtin_fmaf(fa[h].z, e4[h].z, acc0[ki]);
                acc0[ki] = __builtin_fmaf(fa[h].w, e4[h].w, acc0[ki]);
            }
#pragma unroll
            for (int h = 0; h < 8; ++h) {
                acc1[ki] = __builtin_fmaf(fb[h].x, e4[h].x, acc1[ki]);
                acc1[ki] = __builtin_fmaf(fb[h].y, e4[h].y, acc1[ki]);
                acc1[ki] = __builtin_fmaf(fb[h].z, e4[h].z, acc1[ki]);
                acc1[ki] = __builtin_fmaf(fb[h].w, e4[h].w, acc1[ki]);
            }
#pragma unroll
            for (int h = 0; h < 8; ++h) {
                acc2[ki] = __builtin_fmaf(fc[h].x, e4[h].x, acc2[ki]);
                acc2[ki] = __builtin_fmaf(fc[h].y, e4[h].y, acc2[ki]);
                acc2[ki] = __builtin_fmaf(fc[h].z, e4[h].z, acc2[ki]);
                acc2[ki] = __builtin_fmaf(fc[h].w, e4[h].w, acc2[ki]);
            }
#pragma unroll
            for (int h = 0; h < 8; ++h) {
                acc3[ki] = __builtin_fmaf(fd[h].x, e4[h].x, acc3[ki]);
                acc3[ki] = __builtin_fmaf(fd[h].y, e4[h].y, acc3[ki]);
                acc3[ki] = __builtin_fmaf(fd[h].z, e4[h].z, acc3[ki]);
                acc3[ki] = __builtin_fmaf(fd[h].w, e4[h].w, acc3[ki]);
            }
        }
    }

    if constexpr (SUMSQ) {
#pragma clang fp contract(off)
        a0 = aH00 + aH01; a1 = aH10 + aH11; a2 = aH20 + aH21; a3 = aH30 + aH31;
    }

    // epilogue: ascending k, strict < (first-index ties), numpy formula
    {
#pragma clang fp contract(off)
#pragma unroll
        for (int ki = 0; ki < KN; ++ki) {
            const int k = K0 + ki;
            const float sb = sB[k];
            float t0 = a0 + sb;        // fl(a + b_k)
            float u0 = 2.0f * acc0[ki];
            float d0 = t0 - u0;        // fl(t1 - u)
            if (d0 < best0) { best0 = d0; bidx0 = k; }
            float t1 = a1 + sb;
            float u1 = 2.0f * acc1[ki];
            float d1 = t1 - u1;
            if (d1 < best1) { best1 = d1; bidx1 = k; }
            float t2 = a2 + sb;
            float u2 = 2.0f * acc2[ki];
            float d2 = t2 - u2;
            if (d2 < best2) { best2 = d2; bidx2 = k; }
            float t3 = a3 + sb;
            float u3 = 2.0f * acc3[ki];
            float d3 = t3 - u3;
            if (d3 < best3) { best3 = d3; bidx3 = k; }
        }
    }
}

// FOUR ROWS PER THREAD, k-chunked 17/17/16. R0-R5 model: kernel is bound by
// per-wave e-delivery (2400 ds_read_b128/wave, amortized by rows/thread R).
// R=2 gave 155us (96us DS floor + exposure). R=4 halves DS to ~48us ~ HBM ~
// FMA floors. R=4 -> 4 waves/CU = 1 wave/SIMD -> launch_bounds(64,1) grants
// the full 512-reg budget; k-chunking keeps acc static-indexed with ~18KB
// per-phase bodies (I$-resident) at ~280 peak regs. Cost: x re-read 3x
// (+402MB, L3-resident: x=201MB < 256MB L3).
__global__ __launch_bounds__(64, 1) void vq_fused(
    const float* __restrict__ x, const float* __restrict__ ew,
    float* __restrict__ out_q, float* __restrict__ out_idx,
    float* __restrict__ out_loss, int N)
{
    __shared__ __align__(16) float sE[NUM_EMB * ESTRIDE];
    __shared__ float sB[NUM_EMB];

    for (int i = threadIdx.x; i < NUM_EMB * EMB_DIM; i += blockDim.x) {
        int k = i / EMB_DIM, j = i - k * EMB_DIM;
        sE[k * ESTRIDE + j] = ew[i];
    }
    __syncthreads();
    if (threadIdx.x < NUM_EMB)
        sB[threadIdx.x] = np_sumsq_192(&sE[threadIdx.x * ESTRIDE]);
    __syncthreads();

    // block = 1 wave of 64; thread owns rows r0 + q*(N/4), q=0..3
    const int lane = threadIdx.x;
    const int r0 = blockIdx.x * 64 + lane;  // grid = N/256 exact
    const int Q = N >> 2;
    const float4* xg0 = (const float4*)(x + (size_t)r0 * EMB_DIM);
    const float4* xg1 = (const float4*)(x + (size_t)(r0 + Q) * EMB_DIM);
    const float4* xg2 = (const float4*)(x + (size_t)(r0 + 2 * Q) * EMB_DIM);
    const float4* xg3 = (const float4*)(x + (size_t)(r0 + 3 * Q) * EMB_DIM);

    float a0, a1, a2, a3;
    float best0 = FLT_MAX, best1 = FLT_MAX, best2 = FLT_MAX, best3 = FLT_MAX;
    int bidx0 = 0, bidx1 = 0, bidx2 = 0, bidx3 = 0;

    process_kblock< 0, 17, true >(xg0, xg1, xg2, xg3, sE, sB, a0, a1, a2, a3,
                                  best0, best1, best2, best3, bidx0, bidx1, bidx2, bidx3);
    process_kblock<17, 17, false>(xg0, xg1, xg2, xg3, sE, sB, a0, a1, a2, a3,
                                  best0, best1, best2, best3, bidx0, bidx1, bidx2, bidx3);
    process_kblock<34, 16, false>(xg0, xg1, xg2, xg3, sE, sB, a0, a1, a2, a3,
                                  best0, best1, best2, best3, bidx0, bidx1, bidx2, bidx3);

    out_idx[r0] = (float)bidx0;
    out_idx[r0 + Q] = (float)bidx1;
    out_idx[r0 + 2 * Q] = (float)bidx2;
    out_idx[r0 + 3 * Q] = (float)bidx3;

    // loss: per-wave shuffle reduce + one atomic (pre-add the 4 rows)
    float contrib = (best0 + best1) + (best2 + best3);
#pragma unroll
    for (int off = 1; off < 64; off <<= 1) contrib += __shfl_xor(contrib, off);
    if (lane == 0) atomicAdd(out_loss, contrib);

    // fused coalesced quantized-row write (octet pattern), 4 quarters
    {
        const int c = lane & 7;
        const int rr = lane >> 3;
        const int wave0 = blockIdx.x * 64;
#pragma unroll
        for (int qtr = 0; qtr < 4; ++qtr) {
            const int srcIdx = (qtr == 0) ? bidx0 : (qtr == 1) ? bidx1 : (qtr == 2) ? bidx2 : bidx3;
#pragma unroll
            for (int g = 0; g < 8; ++g) {
                const int kk = __shfl(srcIdx, g * 8 + rr);
                const int wrow = wave0 + qtr * Q + g * 8 + rr;
                float4* qrow = (float4*)(out_q + (size_t)wrow * EMB_DIM);
                const float* erow = &sE[kk * ESTRIDE];
#pragma unroll
                for (int t = 0; t < 6; ++t)
                    qrow[c + 8 * t] = *(const float4*)&erow[(c + 8 * t) * 4];
            }
        }
    }
}

__global__ void vq_init(float* out_loss) { out_loss[0] = 0.f; out_loss[1] = 0.f; }

__global__ void vq_finalize(float* __restrict__ out_loss, int N)
{
    double mean = (double)out_loss[0] / ((double)N * (double)EMB_DIM);
    out_loss[0] = (float)(1.25 * mean);  // (1 + BETA) * mean min-dist / elems
    out_loss[1] = 0.f;                   // contrastloss
}

extern "C" void kernel_launch(void* const* d_in, const int* in_sizes, int n_in,
                              void* d_out, int out_size, void* d_ws, size_t ws_size,
                              hipStream_t stream)
{
    const float* x  = (const float*)d_in[0];
    const float* ew = (const float*)d_in[1];
    const int N = in_sizes[0] / EMB_DIM;  // 262144 (divisible by 256)

    float* out_q    = (float*)d_out;
    float* out_idx  = out_q + (size_t)N * EMB_DIM;
    float* out_loss = out_idx + N;

    vq_init<<<1, 1, 0, stream>>>(out_loss);
    vq_fused<<<N / 256, 64, 0, stream>>>(x, ew, out_q, out_idx, out_loss, N);
    vq_finalize<<<1, 1, 0, stream>>>(out_loss, N);
}